// Round 2
// baseline (2130.333 us; speedup 1.0000x reference)
//
#include <hip/hip_runtime.h>
#include <hip/hip_bf16.h>
#include <math.h>

// MoE top-2 GLU, fp32, MI355X. Sparse (gather) formulation — exactly matches
// the dense reference because combine-weights are 0 for unselected experts.
// (Round 2 resubmit: round 1 failed on GPU acquisition, no signal.)
//
// ws layout:
//   [0,32)      float P_acc[8]         (mean-prob accumulators)
//   [32,64)     int   counts[8]        (tokens per expert)
//   [64,96)     int   offsets[8]       (exclusive prefix of counts)
//   [128, +128K)   int   list_tok[8*T]
//   [+128K, +256K) float list_w [8*T]
//   [1MB, 1MB+64MB) float H[2*T][D_FF]   (compact GLU activations)

#define D_MODEL 1024
#define D_FF    2048
#define NE      8

#define RT 32      // token rows per block tile
#define FC 128     // ff / out cols per block tile
#define KT 16      // K-tile
#define XS_LD 36   // padded LDS stride for 32-row tiles (144B, 16B-aligned)
#define WS_LD 132  // padded LDS stride for 128-col tiles (528B, 16B-aligned)

__device__ __forceinline__ float silu_f(float v) { return v / (1.f + expf(-v)); }

__global__ __launch_bounds__(256) void init_kernel(float* __restrict__ out, int n,
                                                   int* __restrict__ ws0) {
  int i = blockIdx.x * 256 + threadIdx.x;
  if (i < n) out[i] = 0.f;
  if (blockIdx.x == 0 && threadIdx.x < 32) ws0[threadIdx.x] = 0;  // P_acc + counts
}

// One wave per token: logits (8 dots of 1024), softmax, top-2, renorm,
// aux-loss atomics, expert-list append.
__global__ __launch_bounds__(64) void router_kernel(
    const float* __restrict__ x, const float* __restrict__ wr,
    float* __restrict__ P_acc, int* __restrict__ counts,
    int* __restrict__ list_tok, float* __restrict__ list_w, int T) {
  int t = blockIdx.x;
  int lane = threadIdx.x;
  const float4* xr = reinterpret_cast<const float4*>(x + (size_t)t * D_MODEL);
  float4 xv[4];
#pragma unroll
  for (int j = 0; j < 4; ++j) xv[j] = xr[lane + 64 * j];  // unit-stride per instr

  float logit[NE];
#pragma unroll
  for (int e = 0; e < NE; ++e) {
    const float4* wrow = reinterpret_cast<const float4*>(wr + e * D_MODEL);
    float s = 0.f;
#pragma unroll
    for (int j = 0; j < 4; ++j) {
      float4 w4 = wrow[lane + 64 * j];
      s += xv[j].x * w4.x + xv[j].y * w4.y + xv[j].z * w4.z + xv[j].w * w4.w;
    }
#pragma unroll
    for (int off = 32; off > 0; off >>= 1) s += __shfl_xor(s, off, 64);
    logit[e] = s;  // all 64 lanes hold the full sum
  }

  float m = logit[0];
#pragma unroll
  for (int e = 1; e < NE; ++e) m = fmaxf(m, logit[e]);
  float p[NE], sum = 0.f;
#pragma unroll
  for (int e = 0; e < NE; ++e) { p[e] = expf(logit[e] - m); sum += p[e]; }
  float inv = 1.f / sum;
#pragma unroll
  for (int e = 0; e < NE; ++e) p[e] *= inv;

  // top-2 (strict > : lowest index wins ties, matching lax.top_k)
  float v0 = -1.f; int i0 = 0;
#pragma unroll
  for (int e = 0; e < NE; ++e) if (p[e] > v0) { v0 = p[e]; i0 = e; }
  float v1 = -1.f; int i1 = 0;
#pragma unroll
  for (int e = 0; e < NE; ++e) if (e != i0 && p[e] > v1) { v1 = p[e]; i1 = e; }
  float rs = 1.f / (v0 + v1);

  if (lane < NE) atomicAdd(&P_acc[lane], p[lane]);
  if (lane == 0) {
    int pos0 = atomicAdd(&counts[i0], 1);
    list_tok[i0 * T + pos0] = t;
    list_w[i0 * T + pos0] = v0 * rs;
    int pos1 = atomicAdd(&counts[i1], 1);
    list_tok[i1 * T + pos1] = t;
    list_w[i1 * T + pos1] = v1 * rs;
  }
}

__global__ void finalize_router(const float* __restrict__ P_acc,
                                const int* __restrict__ counts,
                                int* __restrict__ offsets,
                                float* __restrict__ out_aux, int T) {
  if (threadIdx.x == 0 && blockIdx.x == 0) {
    int off = 0; float aux = 0.f; float invT = 1.f / (float)T;
    for (int e = 0; e < NE; ++e) {
      offsets[e] = off; off += counts[e];
      aux += ((float)counts[e] * invT) * (P_acc[e] * invT);
    }
    out_aux[0] = aux * (float)NE * 0.01f;
  }
}

// H[row, fc] = silu(x@Wg^T) * (x@Wu^T) for this expert's token rows.
__global__ __launch_bounds__(256) void glu_kernel(
    const float* __restrict__ x, const float* __restrict__ w_gate,
    const float* __restrict__ w_up, const int* __restrict__ counts,
    const int* __restrict__ offsets, const int* __restrict__ list_tok,
    float* __restrict__ H, int T) {
  const int tiles_r = T / RT;
  int e = blockIdx.x / tiles_r;
  int row0 = (blockIdx.x % tiles_r) * RT;
  int cnt = counts[e];
  if (row0 >= cnt) return;
  int rv = cnt - row0; if (rv > RT) rv = RT;
  int fc0 = blockIdx.y * FC;

  __shared__ float Xs[KT][XS_LD];
  __shared__ float Gs[KT][WS_LD];
  __shared__ float Us[KT][WS_LD];

  int tid = threadIdx.x;
  int tx = tid & 15, ty = tid >> 4;   // output mapping: rows ty*2+{0,1}, cols tx*4 & 64+tx*4
  int lr = tid >> 2, lq = tid & 3;    // staging mapping

  const float* xrow = x;  // dummy valid
  if (lr < RT) {
    int rr = (lr < rv) ? lr : 0;
    xrow = x + (size_t)list_tok[e * T + row0 + rr] * D_MODEL;
  }
  const float* gp0 = w_gate + ((size_t)e * D_FF + fc0 + lr) * D_MODEL;
  const float* up0 = w_up   + ((size_t)e * D_FF + fc0 + lr) * D_MODEL;
  const float* gp1 = gp0 + (size_t)64 * D_MODEL;
  const float* up1 = up0 + (size_t)64 * D_MODEL;

  float accg[2][8] = {{0}}, accu[2][8] = {{0}};

  for (int k0 = 0; k0 < D_MODEL; k0 += KT) {
    float4 xa = make_float4(0, 0, 0, 0);
    if (lr < RT) xa = *(const float4*)(xrow + k0 + lq * 4);
    float4 ga0 = *(const float4*)(gp0 + k0 + lq * 4);
    float4 ga1 = *(const float4*)(gp1 + k0 + lq * 4);
    float4 ua0 = *(const float4*)(up0 + k0 + lq * 4);
    float4 ua1 = *(const float4*)(up1 + k0 + lq * 4);
    __syncthreads();
    if (lr < RT) {
      Xs[lq * 4 + 0][lr] = xa.x; Xs[lq * 4 + 1][lr] = xa.y;
      Xs[lq * 4 + 2][lr] = xa.z; Xs[lq * 4 + 3][lr] = xa.w;
    }
    Gs[lq * 4 + 0][lr] = ga0.x; Gs[lq * 4 + 1][lr] = ga0.y;
    Gs[lq * 4 + 2][lr] = ga0.z; Gs[lq * 4 + 3][lr] = ga0.w;
    Gs[lq * 4 + 0][64 + lr] = ga1.x; Gs[lq * 4 + 1][64 + lr] = ga1.y;
    Gs[lq * 4 + 2][64 + lr] = ga1.z; Gs[lq * 4 + 3][64 + lr] = ga1.w;
    Us[lq * 4 + 0][lr] = ua0.x; Us[lq * 4 + 1][lr] = ua0.y;
    Us[lq * 4 + 2][lr] = ua0.z; Us[lq * 4 + 3][lr] = ua0.w;
    Us[lq * 4 + 0][64 + lr] = ua1.x; Us[lq * 4 + 1][64 + lr] = ua1.y;
    Us[lq * 4 + 2][64 + lr] = ua1.z; Us[lq * 4 + 3][64 + lr] = ua1.w;
    __syncthreads();
#pragma unroll
    for (int kk = 0; kk < KT; ++kk) {
      float x0 = Xs[kk][ty * 2 + 0];
      float x1 = Xs[kk][ty * 2 + 1];
      float4 gA = *(const float4*)&Gs[kk][tx * 4];
      float4 gB = *(const float4*)&Gs[kk][64 + tx * 4];
      float4 uA = *(const float4*)&Us[kk][tx * 4];
      float4 uB = *(const float4*)&Us[kk][64 + tx * 4];
      accg[0][0] += x0 * gA.x; accg[0][1] += x0 * gA.y; accg[0][2] += x0 * gA.z; accg[0][3] += x0 * gA.w;
      accg[0][4] += x0 * gB.x; accg[0][5] += x0 * gB.y; accg[0][6] += x0 * gB.z; accg[0][7] += x0 * gB.w;
      accg[1][0] += x1 * gA.x; accg[1][1] += x1 * gA.y; accg[1][2] += x1 * gA.z; accg[1][3] += x1 * gA.w;
      accg[1][4] += x1 * gB.x; accg[1][5] += x1 * gB.y; accg[1][6] += x1 * gB.z; accg[1][7] += x1 * gB.w;
      accu[0][0] += x0 * uA.x; accu[0][1] += x0 * uA.y; accu[0][2] += x0 * uA.z; accu[0][3] += x0 * uA.w;
      accu[0][4] += x0 * uB.x; accu[0][5] += x0 * uB.y; accu[0][6] += x0 * uB.z; accu[0][7] += x0 * uB.w;
      accu[1][0] += x1 * uA.x; accu[1][1] += x1 * uA.y; accu[1][2] += x1 * uA.z; accu[1][3] += x1 * uA.w;
      accu[1][4] += x1 * uB.x; accu[1][5] += x1 * uB.y; accu[1][6] += x1 * uB.z; accu[1][7] += x1 * uB.w;
    }
  }

  int hbase = offsets[e] + row0;
#pragma unroll
  for (int r = 0; r < 2; ++r) {
    int rr = ty * 2 + r;
    if (rr < rv) {
      float* hp = H + (size_t)(hbase + rr) * D_FF + fc0;
      float4 hA, hB;
      hA.x = silu_f(accg[r][0]) * accu[r][0]; hA.y = silu_f(accg[r][1]) * accu[r][1];
      hA.z = silu_f(accg[r][2]) * accu[r][2]; hA.w = silu_f(accg[r][3]) * accu[r][3];
      hB.x = silu_f(accg[r][4]) * accu[r][4]; hB.y = silu_f(accg[r][5]) * accu[r][5];
      hB.z = silu_f(accg[r][6]) * accu[r][6]; hB.w = silu_f(accg[r][7]) * accu[r][7];
      *(float4*)(hp + tx * 4) = hA;
      *(float4*)(hp + 64 + tx * 4) = hB;
    }
  }
}

// out[tok, dc] += w * (H_row @ Wd^T). Exactly 2 contributions per element.
__global__ __launch_bounds__(256) void down_kernel(
    const float* __restrict__ H, const float* __restrict__ w_down,
    const int* __restrict__ counts, const int* __restrict__ offsets,
    const int* __restrict__ list_tok, const float* __restrict__ list_w,
    float* __restrict__ out, int T) {
  const int tiles_r = T / RT;
  int e = blockIdx.x / tiles_r;
  int row0 = (blockIdx.x % tiles_r) * RT;
  int cnt = counts[e];
  if (row0 >= cnt) return;
  int rv = cnt - row0; if (rv > RT) rv = RT;
  int dc0 = blockIdx.y * FC;

  __shared__ float Hs[KT][XS_LD];
  __shared__ float Ds[KT][WS_LD];

  int tid = threadIdx.x;
  int tx = tid & 15, ty = tid >> 4;
  int lr = tid >> 2, lq = tid & 3;

  int hbase = offsets[e] + row0;
  const float* hrow = H;
  if (lr < RT) {
    int rr = (lr < rv) ? lr : 0;
    hrow = H + (size_t)(hbase + rr) * D_FF;
  }
  const float* dp0 = w_down + ((size_t)e * D_MODEL + dc0 + lr) * D_FF;
  const float* dp1 = dp0 + (size_t)64 * D_FF;

  float acc[2][8] = {{0}};

  for (int k0 = 0; k0 < D_FF; k0 += KT) {
    float4 ha = make_float4(0, 0, 0, 0);
    if (lr < RT) ha = *(const float4*)(hrow + k0 + lq * 4);
    float4 da0 = *(const float4*)(dp0 + k0 + lq * 4);
    float4 da1 = *(const float4*)(dp1 + k0 + lq * 4);
    __syncthreads();
    if (lr < RT) {
      Hs[lq * 4 + 0][lr] = ha.x; Hs[lq * 4 + 1][lr] = ha.y;
      Hs[lq * 4 + 2][lr] = ha.z; Hs[lq * 4 + 3][lr] = ha.w;
    }
    Ds[lq * 4 + 0][lr] = da0.x; Ds[lq * 4 + 1][lr] = da0.y;
    Ds[lq * 4 + 2][lr] = da0.z; Ds[lq * 4 + 3][lr] = da0.w;
    Ds[lq * 4 + 0][64 + lr] = da1.x; Ds[lq * 4 + 1][64 + lr] = da1.y;
    Ds[lq * 4 + 2][64 + lr] = da1.z; Ds[lq * 4 + 3][64 + lr] = da1.w;
    __syncthreads();
#pragma unroll
    for (int kk = 0; kk < KT; ++kk) {
      float h0 = Hs[kk][ty * 2 + 0];
      float h1 = Hs[kk][ty * 2 + 1];
      float4 dA = *(const float4*)&Ds[kk][tx * 4];
      float4 dB = *(const float4*)&Ds[kk][64 + tx * 4];
      acc[0][0] += h0 * dA.x; acc[0][1] += h0 * dA.y; acc[0][2] += h0 * dA.z; acc[0][3] += h0 * dA.w;
      acc[0][4] += h0 * dB.x; acc[0][5] += h0 * dB.y; acc[0][6] += h0 * dB.z; acc[0][7] += h0 * dB.w;
      acc[1][0] += h1 * dA.x; acc[1][1] += h1 * dA.y; acc[1][2] += h1 * dA.z; acc[1][3] += h1 * dA.w;
      acc[1][4] += h1 * dB.x; acc[1][5] += h1 * dB.y; acc[1][6] += h1 * dB.z; acc[1][7] += h1 * dB.w;
    }
  }

#pragma unroll
  for (int r = 0; r < 2; ++r) {
    int rr = ty * 2 + r;
    if (rr < rv) {
      float w = list_w[e * T + row0 + rr];
      int tok = list_tok[e * T + row0 + rr];
      float* op = out + (size_t)tok * D_MODEL + dc0;
#pragma unroll
      for (int c = 0; c < 4; ++c) atomicAdd(op + tx * 4 + c, w * acc[r][c]);
#pragma unroll
      for (int c = 0; c < 4; ++c) atomicAdd(op + 64 + tx * 4 + c, w * acc[r][4 + c]);
    }
  }
}

extern "C" void kernel_launch(void* const* d_in, const int* in_sizes, int n_in,
                              void* d_out, int out_size, void* d_ws, size_t ws_size,
                              hipStream_t stream) {
  const float* x        = (const float*)d_in[0];
  const float* w_router = (const float*)d_in[1];
  const float* w_gate   = (const float*)d_in[2];
  const float* w_up     = (const float*)d_in[3];
  const float* w_down   = (const float*)d_in[4];
  float* out = (float*)d_out;
  int T = in_sizes[0] / D_MODEL;  // 4096

  char* ws = (char*)d_ws;
  float* P_acc   = (float*)ws;
  int*   counts  = (int*)(ws + 32);
  int*   offsets = (int*)(ws + 64);
  int*   list_tok = (int*)(ws + 128);
  float* list_w   = (float*)(ws + 128 + (size_t)NE * T * 4);
  float* H        = (float*)(ws + (1u << 20));

  int n_out = T * D_MODEL + 1;
  init_kernel<<<(n_out + 255) / 256, 256, 0, stream>>>(out, n_out, (int*)ws);
  router_kernel<<<T, 64, 0, stream>>>(x, w_router, P_acc, counts, list_tok, list_w, T);
  finalize_router<<<1, 64, 0, stream>>>(P_acc, counts, offsets, out + (size_t)T * D_MODEL, T);
  glu_kernel<<<dim3(NE * (T / RT), D_FF / FC), 256, 0, stream>>>(
      x, w_gate, w_up, counts, offsets, list_tok, H, T);
  down_kernel<<<dim3(NE * (T / RT), D_MODEL / FC), 256, 0, stream>>>(
      H, w_down, counts, offsets, list_tok, list_w, out, T);
}

// Round 3
// 971.517 us; speedup vs baseline: 2.1928x; 2.1928x over previous
//
#include <hip/hip_runtime.h>
#include <hip/hip_bf16.h>
#include <math.h>
#include <stdint.h>

// MoE top-2 GLU, MI355X round 3: fp16 MFMA (f32 accumulate) GEMMs.
// Pipeline: init -> conv_w (fp32->fp16 weights) -> router (+x->fp16) ->
//           finalize -> glu_mfma (gate&up) -> combine (silu*u, in-place) ->
//           down_mfma (scatter atomicAdd, exactly 2 adds/elem).
//
// ws layout (bytes):
//   [0,32)    float P_acc[8]
//   [32,64)   int counts[8]
//   [64,96)   int offsets[8]
//   [4K, +128K)   int   list_tok[8*T]
//   [4K+128K, +128K) float list_w[8*T]
//   [1M, 9M)     fp16 xh[T][1024]
//   [9M, 41M)    fp16 wgh[8][2048][1024]
//   [41M, 73M)   fp16 wuh[8][2048][1024]
//   [73M, 105M)  fp16 wdh[8][1024][2048]
//   [105M,137M)  fp16 Gbuf[8192][2048]  (gate preact, then H in-place)
//   [137M,169M)  fp16 Ubuf[8192][2048]

#define D_MODEL 1024
#define D_FF    2048
#define NE      8
#define BM 128
#define BN 128
#define BK 64

typedef _Float16 f16x8 __attribute__((ext_vector_type(8)));
typedef _Float16 f16x4 __attribute__((ext_vector_type(4)));
typedef float    f32x4 __attribute__((ext_vector_type(4)));

__device__ __forceinline__ void gload16(const void* src, void* dst) {
  __builtin_amdgcn_global_load_lds(
      (const __attribute__((address_space(1))) uint32_t*)(uintptr_t)src,
      (__attribute__((address_space(3))) uint32_t*)(uint32_t)(uintptr_t)dst,
      16, 0, 0);
}

__global__ __launch_bounds__(256) void init_kernel(float* __restrict__ out, int n,
                                                   int* __restrict__ ws0) {
  int i = blockIdx.x * 256 + threadIdx.x;
  if (i < n) out[i] = 0.f;
  if (blockIdx.x == 0 && threadIdx.x < 32) ws0[threadIdx.x] = 0;  // P_acc + counts
}

// fp32 -> fp16 for the three expert weight tensors (equal sizes).
__global__ __launch_bounds__(256) void conv_w(
    const float4* __restrict__ a, const float4* __restrict__ b,
    const float4* __restrict__ c, f16x4* __restrict__ da,
    f16x4* __restrict__ db, f16x4* __restrict__ dc, int n4) {
  int stride = gridDim.x * 256;
  for (int i = blockIdx.x * 256 + threadIdx.x; i < n4; i += stride) {
    float4 v = a[i];
    f16x4 h; h[0] = (_Float16)v.x; h[1] = (_Float16)v.y; h[2] = (_Float16)v.z; h[3] = (_Float16)v.w;
    da[i] = h;
    v = b[i];
    h[0] = (_Float16)v.x; h[1] = (_Float16)v.y; h[2] = (_Float16)v.z; h[3] = (_Float16)v.w;
    db[i] = h;
    v = c[i];
    h[0] = (_Float16)v.x; h[1] = (_Float16)v.y; h[2] = (_Float16)v.z; h[3] = (_Float16)v.w;
    dc[i] = h;
  }
}

// One wave per token: logits, softmax, top-2 (strict >, low index wins ties),
// renorm, aux atomics, expert-list append, and x -> fp16.
__global__ __launch_bounds__(64) void router_kernel(
    const float* __restrict__ x, const float* __restrict__ wr,
    float* __restrict__ P_acc, int* __restrict__ counts,
    int* __restrict__ list_tok, float* __restrict__ list_w,
    _Float16* __restrict__ xh, int T) {
  int t = blockIdx.x;
  int lane = threadIdx.x;
  const float4* xr = reinterpret_cast<const float4*>(x + (size_t)t * D_MODEL);
  f16x4* xo = reinterpret_cast<f16x4*>(xh + (size_t)t * D_MODEL);
  float4 xv[4];
#pragma unroll
  for (int j = 0; j < 4; ++j) {
    xv[j] = xr[lane + 64 * j];
    f16x4 h; h[0] = (_Float16)xv[j].x; h[1] = (_Float16)xv[j].y;
    h[2] = (_Float16)xv[j].z; h[3] = (_Float16)xv[j].w;
    xo[lane + 64 * j] = h;
  }

  float logit[NE];
#pragma unroll
  for (int e = 0; e < NE; ++e) {
    const float4* wrow = reinterpret_cast<const float4*>(wr + e * D_MODEL);
    float s = 0.f;
#pragma unroll
    for (int j = 0; j < 4; ++j) {
      float4 w4 = wrow[lane + 64 * j];
      s += xv[j].x * w4.x + xv[j].y * w4.y + xv[j].z * w4.z + xv[j].w * w4.w;
    }
#pragma unroll
    for (int off = 32; off > 0; off >>= 1) s += __shfl_xor(s, off, 64);
    logit[e] = s;
  }

  float m = logit[0];
#pragma unroll
  for (int e = 1; e < NE; ++e) m = fmaxf(m, logit[e]);
  float p[NE], sum = 0.f;
#pragma unroll
  for (int e = 0; e < NE; ++e) { p[e] = expf(logit[e] - m); sum += p[e]; }
  float inv = 1.f / sum;
#pragma unroll
  for (int e = 0; e < NE; ++e) p[e] *= inv;

  float v0 = -1.f; int i0 = 0;
#pragma unroll
  for (int e = 0; e < NE; ++e) if (p[e] > v0) { v0 = p[e]; i0 = e; }
  float v1 = -1.f; int i1 = 0;
#pragma unroll
  for (int e = 0; e < NE; ++e) if (e != i0 && p[e] > v1) { v1 = p[e]; i1 = e; }
  float rs = 1.f / (v0 + v1);

  if (lane < NE) atomicAdd(&P_acc[lane], p[lane]);
  if (lane == 0) {
    int pos0 = atomicAdd(&counts[i0], 1);
    list_tok[i0 * T + pos0] = t;
    list_w[i0 * T + pos0] = v0 * rs;
    int pos1 = atomicAdd(&counts[i1], 1);
    list_tok[i1 * T + pos1] = t;
    list_w[i1 * T + pos1] = v1 * rs;
  }
}

__global__ void finalize_router(const float* __restrict__ P_acc,
                                const int* __restrict__ counts,
                                int* __restrict__ offsets,
                                float* __restrict__ out_aux, int T) {
  if (threadIdx.x == 0 && blockIdx.x == 0) {
    int off = 0; float aux = 0.f; float invT = 1.f / (float)T;
    for (int e = 0; e < NE; ++e) {
      offsets[e] = off; off += counts[e];
      aux += ((float)counts[e] * invT) * (P_acc[e] * invT);
    }
    out_aux[0] = aux * (float)NE * 0.01f;
  }
}

// C[m,n] = A[m,:] . W[n,:]   (A = gathered x rows fp16, W = gate or up fp16)
// 128x128 tile, BK=64, 4 waves (2x2), 64x64 per wave, mfma 16x16x32 f16.
// LDS tiles [128][64] fp16 with XOR swizzle byte^=((row&7)<<4):
// linear global_load_lds dest + inverse-swizzled source + swizzled ds_read.
__global__ __launch_bounds__(256) void glu_mfma(
    const _Float16* __restrict__ xh, const _Float16* __restrict__ wgh,
    const _Float16* __restrict__ wuh, const int* __restrict__ counts,
    const int* __restrict__ offsets, const int* __restrict__ list_tok,
    _Float16* __restrict__ Gbuf, _Float16* __restrict__ Ubuf, int T) {
  int e = blockIdx.x >> 5, tile = blockIdx.x & 31;
  int cnt = counts[e];
  int row0 = tile * BM;
  if (row0 >= cnt) return;
  int rv = cnt - row0; if (rv > BM) rv = BM;
  int hbase = offsets[e] + row0;
  int by = blockIdx.y;
  bool isUp = by >= 16;
  int n0 = (by & 15) * BN;
  const _Float16* wsrc = (isUp ? wuh : wgh) + (size_t)e * D_FF * D_MODEL;
  _Float16* obuf = isUp ? Ubuf : Gbuf;

  __shared__ char lds[32768];
  char* ldsA = lds;
  char* ldsB = lds + 16384;

  int tid = threadIdx.x;
  int wave = tid >> 6, lane = tid & 63;
  int wm = wave >> 1, wn = wave & 1;

  int swz = ((lane & 7) ^ (lane >> 3)) << 4;
  const char* srcA[4];
  const char* srcB[4];
#pragma unroll
  for (int c = 0; c < 4; ++c) {
    int row = c * 32 + wave * 8 + (lane >> 3);
    int ra = row < rv ? row : (rv - 1);
    int tok = list_tok[e * T + row0 + ra];
    srcA[c] = (const char*)(xh + (size_t)tok * D_MODEL) + swz;
    srcB[c] = (const char*)(wsrc + (size_t)(n0 + row) * D_MODEL) + swz;
  }

  int aAddr[2][4], bAddr[2][4];
#pragma unroll
  for (int kk = 0; kk < 2; ++kk) {
#pragma unroll
    for (int i = 0; i < 4; ++i) {
      int rowa = wm * 64 + i * 16 + (lane & 15);
      int kb = kk * 64 + (lane >> 4) * 16;
      aAddr[kk][i] = rowa * 128 + (kb ^ ((rowa & 7) << 4));
      int rowb = wn * 64 + i * 16 + (lane & 15);
      bAddr[kk][i] = rowb * 128 + (kb ^ ((rowb & 7) << 4));
    }
  }

  f32x4 acc[4][4] = {};

  for (int k0 = 0; k0 < D_MODEL; k0 += BK) {
    __syncthreads();
#pragma unroll
    for (int c = 0; c < 4; ++c) {
      gload16(srcA[c] + k0 * 2, ldsA + c * 4096 + wave * 1024);
      gload16(srcB[c] + k0 * 2, ldsB + c * 4096 + wave * 1024);
    }
    __syncthreads();
#pragma unroll
    for (int kk = 0; kk < 2; ++kk) {
      f16x8 a[4], b[4];
#pragma unroll
      for (int i = 0; i < 4; ++i) a[i] = *(const f16x8*)(ldsA + aAddr[kk][i]);
#pragma unroll
      for (int j = 0; j < 4; ++j) b[j] = *(const f16x8*)(ldsB + bAddr[kk][j]);
#pragma unroll
      for (int i = 0; i < 4; ++i)
#pragma unroll
        for (int j = 0; j < 4; ++j)
          acc[i][j] = __builtin_amdgcn_mfma_f32_16x16x32_f16(a[i], b[j], acc[i][j], 0, 0, 0);
    }
  }

  // C/D layout: col = lane&15, row = (lane>>4)*4 + r  [m89-verified]
#pragma unroll
  for (int i = 0; i < 4; ++i) {
#pragma unroll
    for (int r = 0; r < 4; ++r) {
      int mrow = wm * 64 + i * 16 + (lane >> 4) * 4 + r;
      if (mrow < rv) {
        _Float16* op = obuf + (size_t)(hbase + mrow) * D_FF + n0 + wn * 64 + (lane & 15);
#pragma unroll
        for (int j = 0; j < 4; ++j) op[j * 16] = (_Float16)acc[i][j][r];
      }
    }
  }
}

// H = silu(G) * U elementwise, written in-place over G (fp16).
__global__ __launch_bounds__(256) void combine_k(_Float16* __restrict__ G,
                                                 const _Float16* __restrict__ U, int n8) {
  int stride = gridDim.x * 256;
  for (int i = blockIdx.x * 256 + threadIdx.x; i < n8; i += stride) {
    f16x8 g = ((const f16x8*)G)[i];
    f16x8 u = ((const f16x8*)U)[i];
    f16x8 h;
#pragma unroll
    for (int k = 0; k < 8; ++k) {
      float gf = (float)g[k];
      float uf = (float)u[k];
      h[k] = (_Float16)(gf / (1.f + expf(-gf)) * uf);
    }
    ((f16x8*)G)[i] = h;
  }
}

// out[tok,:] += w * (H_row . Wd[n,:]) — same GEMM structure, scatter epilogue.
__global__ __launch_bounds__(256) void down_mfma(
    const _Float16* __restrict__ H, const _Float16* __restrict__ wdh,
    const int* __restrict__ counts, const int* __restrict__ offsets,
    const int* __restrict__ list_tok, const float* __restrict__ list_w,
    float* __restrict__ out, int T) {
  int e = blockIdx.x >> 5, tile = blockIdx.x & 31;
  int cnt = counts[e];
  int row0 = tile * BM;
  if (row0 >= cnt) return;
  int rv = cnt - row0; if (rv > BM) rv = BM;
  int hbase = offsets[e] + row0;
  int n0 = blockIdx.y * BN;

  __shared__ char lds[32768];
  char* ldsA = lds;
  char* ldsB = lds + 16384;

  int tid = threadIdx.x;
  int wave = tid >> 6, lane = tid & 63;
  int wm = wave >> 1, wn = wave & 1;

  int swz = ((lane & 7) ^ (lane >> 3)) << 4;
  const char* srcA[4];
  const char* srcB[4];
#pragma unroll
  for (int c = 0; c < 4; ++c) {
    int row = c * 32 + wave * 8 + (lane >> 3);
    int ra = row < rv ? row : (rv - 1);
    srcA[c] = (const char*)(H + (size_t)(hbase + ra) * D_FF) + swz;
    srcB[c] = (const char*)(wdh + (size_t)e * D_MODEL * D_FF + (size_t)(n0 + row) * D_FF) + swz;
  }

  int aAddr[2][4], bAddr[2][4];
#pragma unroll
  for (int kk = 0; kk < 2; ++kk) {
#pragma unroll
    for (int i = 0; i < 4; ++i) {
      int rowa = wm * 64 + i * 16 + (lane & 15);
      int kb = kk * 64 + (lane >> 4) * 16;
      aAddr[kk][i] = rowa * 128 + (kb ^ ((rowa & 7) << 4));
      int rowb = wn * 64 + i * 16 + (lane & 15);
      bAddr[kk][i] = rowb * 128 + (kb ^ ((rowb & 7) << 4));
    }
  }

  f32x4 acc[4][4] = {};

  for (int k0 = 0; k0 < D_FF; k0 += BK) {
    __syncthreads();
#pragma unroll
    for (int c = 0; c < 4; ++c) {
      gload16(srcA[c] + k0 * 2, ldsA + c * 4096 + wave * 1024);
      gload16(srcB[c] + k0 * 2, ldsB + c * 4096 + wave * 1024);
    }
    __syncthreads();
#pragma unroll
    for (int kk = 0; kk < 2; ++kk) {
      f16x8 a[4], b[4];
#pragma unroll
      for (int i = 0; i < 4; ++i) a[i] = *(const f16x8*)(ldsA + aAddr[kk][i]);
#pragma unroll
      for (int j = 0; j < 4; ++j) b[j] = *(const f16x8*)(ldsB + bAddr[kk][j]);
#pragma unroll
      for (int i = 0; i < 4; ++i)
#pragma unroll
        for (int j = 0; j < 4; ++j)
          acc[i][j] = __builtin_amdgcn_mfma_f32_16x16x32_f16(a[i], b[j], acc[i][j], 0, 0, 0);
    }
  }

#pragma unroll
  for (int i = 0; i < 4; ++i) {
#pragma unroll
    for (int r = 0; r < 4; ++r) {
      int mrow = wm * 64 + i * 16 + (lane >> 4) * 4 + r;
      if (mrow < rv) {
        int li = e * T + row0 + mrow;
        float w = list_w[li];
        int tok = list_tok[li];
        float* op = out + (size_t)tok * D_MODEL + n0 + wn * 64 + (lane & 15);
#pragma unroll
        for (int j = 0; j < 4; ++j) atomicAdd(op + j * 16, w * acc[i][j][r]);
      }
    }
  }
}

extern "C" void kernel_launch(void* const* d_in, const int* in_sizes, int n_in,
                              void* d_out, int out_size, void* d_ws, size_t ws_size,
                              hipStream_t stream) {
  const float* x        = (const float*)d_in[0];
  const float* w_router = (const float*)d_in[1];
  const float* w_gate   = (const float*)d_in[2];
  const float* w_up     = (const float*)d_in[3];
  const float* w_down   = (const float*)d_in[4];
  float* out = (float*)d_out;
  int T = in_sizes[0] / D_MODEL;  // 4096

  const size_t MB = 1048576;
  char* ws = (char*)d_ws;
  float* P_acc    = (float*)ws;
  int*   counts   = (int*)(ws + 32);
  int*   offsets  = (int*)(ws + 64);
  int*   list_tok = (int*)(ws + 4096);
  float* list_w   = (float*)(ws + 4096 + 131072);
  _Float16* xh   = (_Float16*)(ws + 1 * MB);
  _Float16* wgh  = (_Float16*)(ws + 9 * MB);
  _Float16* wuh  = (_Float16*)(ws + 41 * MB);
  _Float16* wdh  = (_Float16*)(ws + 73 * MB);
  _Float16* Gbuf = (_Float16*)(ws + 105 * MB);
  _Float16* Ubuf = (_Float16*)(ws + 137 * MB);

  int n_out = T * D_MODEL + 1;
  init_kernel<<<(n_out + 255) / 256, 256, 0, stream>>>(out, n_out, (int*)ws);
  conv_w<<<2048, 256, 0, stream>>>(
      (const float4*)w_gate, (const float4*)w_up, (const float4*)w_down,
      (f16x4*)wgh, (f16x4*)wuh, (f16x4*)wdh, NE * D_FF * D_MODEL / 4);
  router_kernel<<<T, 64, 0, stream>>>(x, w_router, P_acc, counts, list_tok, list_w, xh, T);
  finalize_router<<<1, 64, 0, stream>>>(P_acc, counts, offsets, out + (size_t)T * D_MODEL, T);
  glu_mfma<<<dim3(NE * (T / BM), 2 * D_FF / BN), 256, 0, stream>>>(
      xh, wgh, wuh, counts, offsets, list_tok, Gbuf, Ubuf, T);
  combine_k<<<2048, 256, 0, stream>>>(Gbuf, Ubuf, 2 * T * D_FF / 8);
  down_mfma<<<dim3(NE * (T / BM), D_MODEL / BN), 256, 0, stream>>>(
      Gbuf, wdh, counts, offsets, list_tok, list_w, out, T);
}

// Round 5
// 877.906 us; speedup vs baseline: 2.4266x; 1.1066x over previous
//
#include <hip/hip_runtime.h>
#include <hip/hip_bf16.h>
#include <math.h>
#include <stdint.h>

// MoE top-2 GLU, MI355X round 5 (resubmit of round 4; infra failure, no signal):
// fused gate+up fp16 MFMA GEMM with depth-2 counted-vmcnt pipeline (T3+T4),
// raw s_barrier, 3 LDS buffers.
// Pipeline: init -> conv_w -> router -> finalize -> glu_fused -> down_mfma.
//
// ws layout (bytes):
//   [0,32)    float P_acc[8]; [32,64) int counts[8]; [64,96) int offsets[8]
//   [4K,+128K) int list_tok[8*T]; [4K+128K,+128K) float list_w[8*T]
//   [1M,9M)    fp16 xh[T][1024]
//   [9M,41M)   fp16 wgh[8][2048][1024]
//   [41M,73M)  fp16 wuh[8][2048][1024]
//   [73M,105M) fp16 wdh[8][1024][2048]
//   [105M,137M) fp16 H[8192][2048]

#define D_MODEL 1024
#define D_FF    2048
#define NE      8
#define BM 128
#define BN 128
#define BK 64
#define GLU_BUF 49152   // A 16K @0, Bg 16K @16384, Bu 16K @32768
#define DWN_BUF 32768   // A 16K @0, B 16K @16384

typedef _Float16 f16x8 __attribute__((ext_vector_type(8)));
typedef _Float16 f16x4 __attribute__((ext_vector_type(4)));
typedef float    f32x4 __attribute__((ext_vector_type(4)));

__device__ __forceinline__ void gload16(const void* src, void* dst) {
  __builtin_amdgcn_global_load_lds(
      (const __attribute__((address_space(1))) uint32_t*)(uintptr_t)src,
      (__attribute__((address_space(3))) uint32_t*)(uint32_t)(uintptr_t)dst,
      16, 0, 0);
}

__global__ __launch_bounds__(256) void init_kernel(float* __restrict__ out, int n,
                                                   int* __restrict__ ws0) {
  int i = blockIdx.x * 256 + threadIdx.x;
  if (i < n) out[i] = 0.f;
  if (blockIdx.x == 0 && threadIdx.x < 32) ws0[threadIdx.x] = 0;  // P_acc + counts
}

__global__ __launch_bounds__(256) void conv_w(
    const float4* __restrict__ a, const float4* __restrict__ b,
    const float4* __restrict__ c, f16x4* __restrict__ da,
    f16x4* __restrict__ db, f16x4* __restrict__ dc, int n4) {
  int stride = gridDim.x * 256;
  for (int i = blockIdx.x * 256 + threadIdx.x; i < n4; i += stride) {
    float4 v = a[i];
    f16x4 h; h[0] = (_Float16)v.x; h[1] = (_Float16)v.y; h[2] = (_Float16)v.z; h[3] = (_Float16)v.w;
    da[i] = h;
    v = b[i];
    h[0] = (_Float16)v.x; h[1] = (_Float16)v.y; h[2] = (_Float16)v.z; h[3] = (_Float16)v.w;
    db[i] = h;
    v = c[i];
    h[0] = (_Float16)v.x; h[1] = (_Float16)v.y; h[2] = (_Float16)v.z; h[3] = (_Float16)v.w;
    dc[i] = h;
  }
}

__global__ __launch_bounds__(64) void router_kernel(
    const float* __restrict__ x, const float* __restrict__ wr,
    float* __restrict__ P_acc, int* __restrict__ counts,
    int* __restrict__ list_tok, float* __restrict__ list_w,
    _Float16* __restrict__ xh, int T) {
  int t = blockIdx.x;
  int lane = threadIdx.x;
  const float4* xr = reinterpret_cast<const float4*>(x + (size_t)t * D_MODEL);
  f16x4* xo = reinterpret_cast<f16x4*>(xh + (size_t)t * D_MODEL);
  float4 xv[4];
#pragma unroll
  for (int j = 0; j < 4; ++j) {
    xv[j] = xr[lane + 64 * j];
    f16x4 h; h[0] = (_Float16)xv[j].x; h[1] = (_Float16)xv[j].y;
    h[2] = (_Float16)xv[j].z; h[3] = (_Float16)xv[j].w;
    xo[lane + 64 * j] = h;
  }

  float logit[NE];
#pragma unroll
  for (int e = 0; e < NE; ++e) {
    const float4* wrow = reinterpret_cast<const float4*>(wr + e * D_MODEL);
    float s = 0.f;
#pragma unroll
    for (int j = 0; j < 4; ++j) {
      float4 w4 = wrow[lane + 64 * j];
      s += xv[j].x * w4.x + xv[j].y * w4.y + xv[j].z * w4.z + xv[j].w * w4.w;
    }
#pragma unroll
    for (int off = 32; off > 0; off >>= 1) s += __shfl_xor(s, off, 64);
    logit[e] = s;
  }

  float m = logit[0];
#pragma unroll
  for (int e = 1; e < NE; ++e) m = fmaxf(m, logit[e]);
  float p[NE], sum = 0.f;
#pragma unroll
  for (int e = 0; e < NE; ++e) { p[e] = expf(logit[e] - m); sum += p[e]; }
  float inv = 1.f / sum;
#pragma unroll
  for (int e = 0; e < NE; ++e) p[e] *= inv;

  float v0 = -1.f; int i0 = 0;
#pragma unroll
  for (int e = 0; e < NE; ++e) if (p[e] > v0) { v0 = p[e]; i0 = e; }
  float v1 = -1.f; int i1 = 0;
#pragma unroll
  for (int e = 0; e < NE; ++e) if (e != i0 && p[e] > v1) { v1 = p[e]; i1 = e; }
  float rs = 1.f / (v0 + v1);

  if (lane < NE) atomicAdd(&P_acc[lane], p[lane]);
  if (lane == 0) {
    int pos0 = atomicAdd(&counts[i0], 1);
    list_tok[i0 * T + pos0] = t;
    list_w[i0 * T + pos0] = v0 * rs;
    int pos1 = atomicAdd(&counts[i1], 1);
    list_tok[i1 * T + pos1] = t;
    list_w[i1 * T + pos1] = v1 * rs;
  }
}

__global__ void finalize_router(const float* __restrict__ P_acc,
                                const int* __restrict__ counts,
                                int* __restrict__ offsets,
                                float* __restrict__ out_aux, int T) {
  if (threadIdx.x == 0 && blockIdx.x == 0) {
    int off = 0; float aux = 0.f; float invT = 1.f / (float)T;
    for (int e = 0; e < NE; ++e) {
      offsets[e] = off; off += counts[e];
      aux += ((float)counts[e] * invT) * (P_acc[e] * invT);
    }
    out_aux[0] = aux * (float)NE * 0.01f;
  }
}

// Fused gate+up GEMM + silu*u epilogue. 512 threads = 8 waves (2x4):
// wave tile 64 rows x 32 cols of BOTH gate and up. Depth-2 prefetch,
// 3 x 48KB LDS buffers, counted vmcnt (12/6/0), raw barriers.
__global__ __launch_bounds__(512) void glu_fused(
    const _Float16* __restrict__ xh, const _Float16* __restrict__ wgh,
    const _Float16* __restrict__ wuh, const int* __restrict__ counts,
    const int* __restrict__ offsets, const int* __restrict__ list_tok,
    _Float16* __restrict__ H, int T) {
  extern __shared__ char lds[];
  int e = blockIdx.x >> 5, tile = blockIdx.x & 31;
  int cnt = counts[e];
  int row0 = tile * BM;
  if (row0 >= cnt) return;
  int rv = cnt - row0; if (rv > BM) rv = BM;
  int hbase = offsets[e] + row0;
  int n0 = blockIdx.y * BN;

  int tid = threadIdx.x;
  int wave = tid >> 6, lane = tid & 63;
  int wm = wave >> 2, wn = wave & 3;

  // swizzle: LDS[row][slot] = global[row][slot ^ (row&7)]; read re-XORs.
  int swz = ((lane & 7) ^ ((lane >> 3) & 7)) << 4;
  const char *sA[2], *sG[2], *sU[2];
  const _Float16* wg_e = wgh + (size_t)e * D_FF * D_MODEL;
  const _Float16* wu_e = wuh + (size_t)e * D_FF * D_MODEL;
#pragma unroll
  for (int c = 0; c < 2; ++c) {
    int row = wave * 16 + c * 8 + (lane >> 3);
    int ra = row < rv ? row : (rv - 1);
    int tok = list_tok[e * T + row0 + ra];
    sA[c] = (const char*)(xh + (size_t)tok * D_MODEL) + swz;
    sG[c] = (const char*)(wg_e + (size_t)(n0 + row) * D_MODEL) + swz;
    sU[c] = (const char*)(wu_e + (size_t)(n0 + row) * D_MODEL) + swz;
  }
  int dstA = wave * 2048;  // each wave stages rows [wave*16, wave*16+16)

  int aOff[2][4], bOff[2][2];
#pragma unroll
  for (int kk = 0; kk < 2; ++kk) {
    int kb = kk * 64 + (lane >> 4) * 16;
#pragma unroll
    for (int i = 0; i < 4; ++i) {
      int rowa = wm * 64 + i * 16 + (lane & 15);
      aOff[kk][i] = rowa * 128 + (kb ^ ((rowa & 7) << 4));
    }
#pragma unroll
    for (int j = 0; j < 2; ++j) {
      int rowb = wn * 32 + j * 16 + (lane & 15);
      bOff[kk][j] = rowb * 128 + (kb ^ ((rowb & 7) << 4));
    }
  }

  f32x4 accg[4][2] = {}, accu[4][2] = {};

  auto STAGE = [&](int buf, int k0) {
    char* db = lds + buf * GLU_BUF;
    gload16(sA[0] + k0 * 2, db + dstA);
    gload16(sA[1] + k0 * 2, db + dstA + 1024);
    gload16(sG[0] + k0 * 2, db + 16384 + dstA);
    gload16(sG[1] + k0 * 2, db + 16384 + dstA + 1024);
    gload16(sU[0] + k0 * 2, db + 32768 + dstA);
    gload16(sU[1] + k0 * 2, db + 32768 + dstA + 1024);
  };
  auto COMPUTE = [&](int buf) {
    const char* cb = lds + buf * GLU_BUF;
#pragma unroll
    for (int kk = 0; kk < 2; ++kk) {
      f16x8 a[4], bg[2], bu[2];
#pragma unroll
      for (int i = 0; i < 4; ++i) a[i] = *(const f16x8*)(cb + aOff[kk][i]);
#pragma unroll
      for (int j = 0; j < 2; ++j) bg[j] = *(const f16x8*)(cb + 16384 + bOff[kk][j]);
#pragma unroll
      for (int j = 0; j < 2; ++j) bu[j] = *(const f16x8*)(cb + 32768 + bOff[kk][j]);
#pragma unroll
      for (int i = 0; i < 4; ++i)
#pragma unroll
        for (int j = 0; j < 2; ++j) {
          accg[i][j] = __builtin_amdgcn_mfma_f32_16x16x32_f16(a[i], bg[j], accg[i][j], 0, 0, 0);
          accu[i][j] = __builtin_amdgcn_mfma_f32_16x16x32_f16(a[i], bu[j], accu[i][j], 0, 0, 0);
        }
    }
  };

  const int NT = D_MODEL / BK;  // 16
  STAGE(0, 0);
  STAGE(1, BK);
  int bi = 0;
  for (int t = 0; t < NT - 2; ++t) {
    int nb = bi + 2; if (nb >= 3) nb -= 3;
    STAGE(nb, (t + 2) * BK);
    // outstanding: stage(t),stage(t+1),stage(t+2) = 18; keep 12 -> stage(t) landed
    asm volatile("s_waitcnt vmcnt(12)" ::: "memory");
    __builtin_amdgcn_sched_barrier(0);
    __builtin_amdgcn_s_barrier();        // all waves' stage(t) complete
    COMPUTE(bi);
    __builtin_amdgcn_s_barrier();        // all waves done reading buf bi
    bi = bi + 1 == 3 ? 0 : bi + 1;
  }
  asm volatile("s_waitcnt vmcnt(6)" ::: "memory");
  __builtin_amdgcn_sched_barrier(0);
  __builtin_amdgcn_s_barrier();
  COMPUTE(bi);
  __builtin_amdgcn_s_barrier();
  bi = bi + 1 == 3 ? 0 : bi + 1;
  asm volatile("s_waitcnt vmcnt(0)" ::: "memory");
  __builtin_amdgcn_sched_barrier(0);
  __builtin_amdgcn_s_barrier();
  COMPUTE(bi);

  // epilogue: H = silu(g) * u  (C/D: col=lane&15, row=(lane>>4)*4+r)
#pragma unroll
  for (int i = 0; i < 4; ++i) {
#pragma unroll
    for (int r = 0; r < 4; ++r) {
      int mrow = wm * 64 + i * 16 + (lane >> 4) * 4 + r;
      if (mrow < rv) {
        _Float16* hp = H + (size_t)(hbase + mrow) * D_FF + n0 + wn * 32 + (lane & 15);
#pragma unroll
        for (int j = 0; j < 2; ++j) {
          float g = accg[i][j][r], u = accu[i][j][r];
          hp[j * 16] = (_Float16)(g / (1.f + expf(-g)) * u);
        }
      }
    }
  }
}

// Down-proj GEMM with scatter atomicAdd epilogue. Same pipeline, 32 K-steps.
__global__ __launch_bounds__(512) void down_mfma(
    const _Float16* __restrict__ Hb, const _Float16* __restrict__ wdh,
    const int* __restrict__ counts, const int* __restrict__ offsets,
    const int* __restrict__ list_tok, const float* __restrict__ list_w,
    float* __restrict__ out, int T) {
  extern __shared__ char lds[];
  int e = blockIdx.x >> 5, tile = blockIdx.x & 31;
  int cnt = counts[e];
  int row0 = tile * BM;
  if (row0 >= cnt) return;
  int rv = cnt - row0; if (rv > BM) rv = BM;
  int hbase = offsets[e] + row0;
  int n0 = blockIdx.y * BN;

  int tid = threadIdx.x;
  int wave = tid >> 6, lane = tid & 63;
  int wm = wave >> 2, wn = wave & 3;

  int swz = ((lane & 7) ^ ((lane >> 3) & 7)) << 4;
  const char *sA[2], *sB[2];
  const _Float16* wd_e = wdh + (size_t)e * D_MODEL * D_FF;
#pragma unroll
  for (int c = 0; c < 2; ++c) {
    int row = wave * 16 + c * 8 + (lane >> 3);
    int ra = row < rv ? row : (rv - 1);
    sA[c] = (const char*)(Hb + (size_t)(hbase + ra) * D_FF) + swz;
    sB[c] = (const char*)(wd_e + (size_t)(n0 + row) * D_FF) + swz;
  }
  int dstA = wave * 2048;

  int aOff[2][4], bOff[2][2];
#pragma unroll
  for (int kk = 0; kk < 2; ++kk) {
    int kb = kk * 64 + (lane >> 4) * 16;
#pragma unroll
    for (int i = 0; i < 4; ++i) {
      int rowa = wm * 64 + i * 16 + (lane & 15);
      aOff[kk][i] = rowa * 128 + (kb ^ ((rowa & 7) << 4));
    }
#pragma unroll
    for (int j = 0; j < 2; ++j) {
      int rowb = wn * 32 + j * 16 + (lane & 15);
      bOff[kk][j] = rowb * 128 + (kb ^ ((rowb & 7) << 4));
    }
  }

  f32x4 acc[4][2] = {};

  auto STAGE = [&](int buf, int k0) {
    char* db = lds + buf * DWN_BUF;
    gload16(sA[0] + k0 * 2, db + dstA);
    gload16(sA[1] + k0 * 2, db + dstA + 1024);
    gload16(sB[0] + k0 * 2, db + 16384 + dstA);
    gload16(sB[1] + k0 * 2, db + 16384 + dstA + 1024);
  };
  auto COMPUTE = [&](int buf) {
    const char* cb = lds + buf * DWN_BUF;
#pragma unroll
    for (int kk = 0; kk < 2; ++kk) {
      f16x8 a[4], b[2];
#pragma unroll
      for (int i = 0; i < 4; ++i) a[i] = *(const f16x8*)(cb + aOff[kk][i]);
#pragma unroll
      for (int j = 0; j < 2; ++j) b[j] = *(const f16x8*)(cb + 16384 + bOff[kk][j]);
#pragma unroll
      for (int i = 0; i < 4; ++i)
#pragma unroll
        for (int j = 0; j < 2; ++j)
          acc[i][j] = __builtin_amdgcn_mfma_f32_16x16x32_f16(a[i], b[j], acc[i][j], 0, 0, 0);
    }
  };

  const int NT = D_FF / BK;  // 32
  STAGE(0, 0);
  STAGE(1, BK);
  int bi = 0;
  for (int t = 0; t < NT - 2; ++t) {
    int nb = bi + 2; if (nb >= 3) nb -= 3;
    STAGE(nb, (t + 2) * BK);
    asm volatile("s_waitcnt vmcnt(8)" ::: "memory");
    __builtin_amdgcn_sched_barrier(0);
    __builtin_amdgcn_s_barrier();
    COMPUTE(bi);
    __builtin_amdgcn_s_barrier();
    bi = bi + 1 == 3 ? 0 : bi + 1;
  }
  asm volatile("s_waitcnt vmcnt(4)" ::: "memory");
  __builtin_amdgcn_sched_barrier(0);
  __builtin_amdgcn_s_barrier();
  COMPUTE(bi);
  __builtin_amdgcn_s_barrier();
  bi = bi + 1 == 3 ? 0 : bi + 1;
  asm volatile("s_waitcnt vmcnt(0)" ::: "memory");
  __builtin_amdgcn_sched_barrier(0);
  __builtin_amdgcn_s_barrier();
  COMPUTE(bi);

#pragma unroll
  for (int i = 0; i < 4; ++i) {
#pragma unroll
    for (int r = 0; r < 4; ++r) {
      int mrow = wm * 64 + i * 16 + (lane >> 4) * 4 + r;
      if (mrow < rv) {
        int li = e * T + row0 + mrow;
        float w = list_w[li];
        int tok = list_tok[li];
        float* op = out + (size_t)tok * D_MODEL + n0 + wn * 32 + (lane & 15);
#pragma unroll
        for (int j = 0; j < 2; ++j) atomicAdd(op + j * 16, w * acc[i][j][r]);
      }
    }
  }
}

extern "C" void kernel_launch(void* const* d_in, const int* in_sizes, int n_in,
                              void* d_out, int out_size, void* d_ws, size_t ws_size,
                              hipStream_t stream) {
  const float* x        = (const float*)d_in[0];
  const float* w_router = (const float*)d_in[1];
  const float* w_gate   = (const float*)d_in[2];
  const float* w_up     = (const float*)d_in[3];
  const float* w_down   = (const float*)d_in[4];
  float* out = (float*)d_out;
  int T = in_sizes[0] / D_MODEL;  // 4096

  const size_t MB = 1048576;
  char* ws = (char*)d_ws;
  float* P_acc    = (float*)ws;
  int*   counts   = (int*)(ws + 32);
  int*   offsets  = (int*)(ws + 64);
  int*   list_tok = (int*)(ws + 4096);
  float* list_w   = (float*)(ws + 4096 + 131072);
  _Float16* xh  = (_Float16*)(ws + 1 * MB);
  _Float16* wgh = (_Float16*)(ws + 9 * MB);
  _Float16* wuh = (_Float16*)(ws + 41 * MB);
  _Float16* wdh = (_Float16*)(ws + 73 * MB);
  _Float16* H   = (_Float16*)(ws + 105 * MB);

  hipFuncSetAttribute(reinterpret_cast<const void*>(glu_fused),
                      hipFuncAttributeMaxDynamicSharedMemorySize, 3 * GLU_BUF);
  hipFuncSetAttribute(reinterpret_cast<const void*>(down_mfma),
                      hipFuncAttributeMaxDynamicSharedMemorySize, 3 * DWN_BUF);

  int n_out = T * D_MODEL + 1;
  init_kernel<<<(n_out + 255) / 256, 256, 0, stream>>>(out, n_out, (int*)ws);
  conv_w<<<2048, 256, 0, stream>>>(
      (const float4*)w_gate, (const float4*)w_up, (const float4*)w_down,
      (f16x4*)wgh, (f16x4*)wuh, (f16x4*)wdh, NE * D_FF * D_MODEL / 4);
  router_kernel<<<T, 64, 0, stream>>>(x, w_router, P_acc, counts, list_tok, list_w, xh, T);
  finalize_router<<<1, 64, 0, stream>>>(P_acc, counts, offsets, out + (size_t)T * D_MODEL, T);
  glu_fused<<<dim3(NE * (T / BM), D_FF / BN), 512, 3 * GLU_BUF, stream>>>(
      xh, wgh, wuh, counts, offsets, list_tok, H, T);
  down_mfma<<<dim3(NE * (T / BM), D_MODEL / BN), 512, 3 * DWN_BUF, stream>>>(
      H, wdh, counts, offsets, list_tok, list_w, out, T);
}

// Round 7
// 816.598 us; speedup vs baseline: 2.6088x; 1.0751x over previous
//
#include <hip/hip_runtime.h>
#include <hip/hip_bf16.h>
#include <math.h>
#include <stdint.h>

// MoE top-2 GLU, MI355X round 7 (resubmit of round 6; infra failure, no signal):
// 2-phase issue-early big-tile fp16 MFMA GEMMs.
// glu: 256x(128+128) fused gate+up, BK=64, 8 waves, 2x64KB LDS buffers.
// down: 128x256, 2x48KB. Inline-asm ds_read_b128 (+lgkmcnt+sched_barrier) so the
// compiler cannot insert vmcnt(0) drains before LDS reads. setprio around MFMA.
//
// ws layout (bytes):
//   [0,32) float P_acc[8]; [32,64) int counts[8]; [64,96) int offsets[8]
//   [4K,+128K) int list_tok[8*T]; [4K+128K,+128K) float list_w[8*T]
//   [1M,9M)    fp16 xh[T][1024]
//   [9M,41M)   fp16 wgh[8][2048][1024]
//   [41M,73M)  fp16 wuh[8][2048][1024]
//   [73M,105M) fp16 wdh[8][1024][2048]
//   [105M,137M) fp16 H[8192][2048]

#define D_MODEL 1024
#define D_FF    2048
#define NE      8
#define BK      64

typedef _Float16 f16x8 __attribute__((ext_vector_type(8)));
typedef _Float16 f16x4 __attribute__((ext_vector_type(4)));
typedef float    f32x4 __attribute__((ext_vector_type(4)));

__device__ __forceinline__ void gload16(const void* src, uint32_t ldsoff) {
  __builtin_amdgcn_global_load_lds(
      (const __attribute__((address_space(1))) uint32_t*)(uintptr_t)src,
      (__attribute__((address_space(3))) uint32_t*)(uintptr_t)ldsoff,
      16, 0, 0);
}

// raw LDS read the compiler can't alias-analyze (no auto vmcnt drains)
__device__ __forceinline__ f16x8 ldsr(uint32_t addr) {
  f16x8 d;
  asm volatile("ds_read_b128 %0, %1" : "=v"(d) : "v"(addr));
  return d;
}
#define LGKM0_FENCE() do { \
  asm volatile("s_waitcnt lgkmcnt(0)" ::: "memory"); \
  __builtin_amdgcn_sched_barrier(0); } while (0)
#define VM0_BARRIER() do { \
  asm volatile("s_waitcnt vmcnt(0)" ::: "memory"); \
  __builtin_amdgcn_sched_barrier(0); \
  __builtin_amdgcn_s_barrier(); } while (0)

__global__ __launch_bounds__(256) void init_kernel(float* __restrict__ out, int n,
                                                   int* __restrict__ ws0) {
  int i = blockIdx.x * 256 + threadIdx.x;
  if (i < n) out[i] = 0.f;
  if (blockIdx.x == 0 && threadIdx.x < 32) ws0[threadIdx.x] = 0;  // P_acc + counts
}

__global__ __launch_bounds__(256) void conv_w(
    const float4* __restrict__ a, const float4* __restrict__ b,
    const float4* __restrict__ c, f16x4* __restrict__ da,
    f16x4* __restrict__ db, f16x4* __restrict__ dc, int n4) {
  int stride = gridDim.x * 256;
  for (int i = blockIdx.x * 256 + threadIdx.x; i < n4; i += stride) {
    float4 v = a[i];
    f16x4 h; h[0] = (_Float16)v.x; h[1] = (_Float16)v.y; h[2] = (_Float16)v.z; h[3] = (_Float16)v.w;
    da[i] = h;
    v = b[i];
    h[0] = (_Float16)v.x; h[1] = (_Float16)v.y; h[2] = (_Float16)v.z; h[3] = (_Float16)v.w;
    db[i] = h;
    v = c[i];
    h[0] = (_Float16)v.x; h[1] = (_Float16)v.y; h[2] = (_Float16)v.z; h[3] = (_Float16)v.w;
    dc[i] = h;
  }
}

__global__ __launch_bounds__(64) void router_kernel(
    const float* __restrict__ x, const float* __restrict__ wr,
    float* __restrict__ P_acc, int* __restrict__ counts,
    int* __restrict__ list_tok, float* __restrict__ list_w,
    _Float16* __restrict__ xh, int T) {
  int t = blockIdx.x;
  int lane = threadIdx.x;
  const float4* xr = reinterpret_cast<const float4*>(x + (size_t)t * D_MODEL);
  f16x4* xo = reinterpret_cast<f16x4*>(xh + (size_t)t * D_MODEL);
  float4 xv[4];
#pragma unroll
  for (int j = 0; j < 4; ++j) {
    xv[j] = xr[lane + 64 * j];
    f16x4 h; h[0] = (_Float16)xv[j].x; h[1] = (_Float16)xv[j].y;
    h[2] = (_Float16)xv[j].z; h[3] = (_Float16)xv[j].w;
    xo[lane + 64 * j] = h;
  }

  float logit[NE];
#pragma unroll
  for (int e = 0; e < NE; ++e) {
    const float4* wrow = reinterpret_cast<const float4*>(wr + e * D_MODEL);
    float s = 0.f;
#pragma unroll
    for (int j = 0; j < 4; ++j) {
      float4 w4 = wrow[lane + 64 * j];
      s += xv[j].x * w4.x + xv[j].y * w4.y + xv[j].z * w4.z + xv[j].w * w4.w;
    }
#pragma unroll
    for (int off = 32; off > 0; off >>= 1) s += __shfl_xor(s, off, 64);
    logit[e] = s;
  }

  float m = logit[0];
#pragma unroll
  for (int e = 1; e < NE; ++e) m = fmaxf(m, logit[e]);
  float p[NE], sum = 0.f;
#pragma unroll
  for (int e = 0; e < NE; ++e) { p[e] = expf(logit[e] - m); sum += p[e]; }
  float inv = 1.f / sum;
#pragma unroll
  for (int e = 0; e < NE; ++e) p[e] *= inv;

  float v0 = -1.f; int i0 = 0;
#pragma unroll
  for (int e = 0; e < NE; ++e) if (p[e] > v0) { v0 = p[e]; i0 = e; }
  float v1 = -1.f; int i1 = 0;
#pragma unroll
  for (int e = 0; e < NE; ++e) if (e != i0 && p[e] > v1) { v1 = p[e]; i1 = e; }
  float rs = 1.f / (v0 + v1);

  if (lane < NE) atomicAdd(&P_acc[lane], p[lane]);
  if (lane == 0) {
    int pos0 = atomicAdd(&counts[i0], 1);
    list_tok[i0 * T + pos0] = t;
    list_w[i0 * T + pos0] = v0 * rs;
    int pos1 = atomicAdd(&counts[i1], 1);
    list_tok[i1 * T + pos1] = t;
    list_w[i1 * T + pos1] = v1 * rs;
  }
}

__global__ void finalize_router(const float* __restrict__ P_acc,
                                const int* __restrict__ counts,
                                int* __restrict__ offsets,
                                float* __restrict__ out_aux, int T) {
  if (threadIdx.x == 0 && blockIdx.x == 0) {
    int off = 0; float aux = 0.f; float invT = 1.f / (float)T;
    for (int e = 0; e < NE; ++e) {
      offsets[e] = off; off += counts[e];
      aux += ((float)counts[e] * invT) * (P_acc[e] * invT);
    }
    out_aux[0] = aux * (float)NE * 0.01f;
  }
}

// Fused gate+up: tile 256 rows x 128 cols (of each), 8 waves (2Mx4N),
// per-wave 128x32(+32). LDS buffer 64KB: A[256][64]@0, G[128][64]@32K, U@48K.
__global__ __launch_bounds__(512) void glu_fused(
    const _Float16* __restrict__ xh, const _Float16* __restrict__ wgh,
    const _Float16* __restrict__ wuh, const int* __restrict__ counts,
    const int* __restrict__ offsets, const int* __restrict__ list_tok,
    _Float16* __restrict__ H, int T) {
  extern __shared__ char lds[];
  const uint32_t LB = (uint32_t)(uintptr_t)lds;
  int e = blockIdx.x >> 4, tile = blockIdx.x & 15;
  int cnt = counts[e];
  int row0 = tile * 256;
  if (row0 >= cnt) return;
  int rv = cnt - row0; if (rv > 256) rv = 256;
  int hbase = offsets[e] + row0;
  int n0 = blockIdx.y * 128;

  int tid = threadIdx.x, wave = tid >> 6, lane = tid & 63;
  int wm = wave >> 2, wn = wave & 3, la = lane & 15;

  // staging sources (inverse-swizzled so linear LDS + swizzled read match)
  int swz = ((lane & 7) ^ ((lane >> 3) & 7)) << 4;
  const char *sA[4], *sG[2], *sU[2];
  const _Float16* wg_e = wgh + (size_t)e * D_FF * D_MODEL;
  const _Float16* wu_e = wuh + (size_t)e * D_FF * D_MODEL;
#pragma unroll
  for (int c = 0; c < 4; ++c) {
    int row = c * 64 + wave * 8 + (lane >> 3);
    int ra = row < rv ? row : (rv - 1);
    int tok = list_tok[e * T + row0 + ra];
    sA[c] = (const char*)(xh + (size_t)tok * D_MODEL) + swz;
  }
#pragma unroll
  for (int c = 0; c < 2; ++c) {
    int row = n0 + c * 64 + wave * 8 + (lane >> 3);
    sG[c] = (const char*)(wg_e + (size_t)row * D_MODEL) + swz;
    sU[c] = (const char*)(wu_e + (size_t)row * D_MODEL) + swz;
  }
  uint32_t dA = wave * 1024;

  // read addressing: row*128 + ((kk*64 + (lane>>4)*16) ^ ((row&7)<<4));
  // row&7 == la&7 for all fragment rows (row = base16*16 + la).
  uint32_t xr_ = (uint32_t)((la & 7) << 4);
  uint32_t colB[2];
#pragma unroll
  for (int kk = 0; kk < 2; ++kk)
    colB[kk] = (uint32_t)(((kk * 64 + (lane >> 4) * 16)) ^ xr_);
  uint32_t aRow[8];
#pragma unroll
  for (int i = 0; i < 8; ++i) aRow[i] = (uint32_t)((wm * 128 + i * 16 + la) * 128);
  uint32_t gRow[2], uRow[2];
#pragma unroll
  for (int j = 0; j < 2; ++j) {
    gRow[j] = 32768u + (uint32_t)((wn * 32 + j * 16 + la) * 128);
    uRow[j] = 49152u + (uint32_t)((wn * 32 + j * 16 + la) * 128);
  }

  f32x4 accg[8][2] = {}, accu[8][2] = {};

  auto STAGE = [&](int buf, int k0) {
    uint32_t db = LB + (uint32_t)buf * 65536u;
#pragma unroll
    for (int c = 0; c < 4; ++c) gload16(sA[c] + k0 * 2, db + c * 8192 + dA);
#pragma unroll
    for (int c = 0; c < 2; ++c) {
      gload16(sG[c] + k0 * 2, db + 32768 + c * 8192 + dA);
      gload16(sU[c] + k0 * 2, db + 49152 + c * 8192 + dA);
    }
  };
  auto COMPUTE = [&](int buf) {
    uint32_t bb = LB + (uint32_t)buf * 65536u;
#pragma unroll
    for (int kk = 0; kk < 2; ++kk) {
      uint32_t cb = colB[kk];
      f16x8 bg0 = ldsr(bb + gRow[0] + cb);
      f16x8 bg1 = ldsr(bb + gRow[1] + cb);
      f16x8 bu0 = ldsr(bb + uRow[0] + cb);
      f16x8 bu1 = ldsr(bb + uRow[1] + cb);
      f16x8 a[8];
#pragma unroll
      for (int i = 0; i < 8; ++i) a[i] = ldsr(bb + aRow[i] + cb);
      LGKM0_FENCE();
      __builtin_amdgcn_s_setprio(1);
#pragma unroll
      for (int i = 0; i < 8; ++i) {
        accg[i][0] = __builtin_amdgcn_mfma_f32_16x16x32_f16(a[i], bg0, accg[i][0], 0, 0, 0);
        accg[i][1] = __builtin_amdgcn_mfma_f32_16x16x32_f16(a[i], bg1, accg[i][1], 0, 0, 0);
        accu[i][0] = __builtin_amdgcn_mfma_f32_16x16x32_f16(a[i], bu0, accu[i][0], 0, 0, 0);
        accu[i][1] = __builtin_amdgcn_mfma_f32_16x16x32_f16(a[i], bu1, accu[i][1], 0, 0, 0);
      }
      __builtin_amdgcn_s_setprio(0);
    }
  };

  const int NT = D_MODEL / BK;  // 16
  STAGE(0, 0);
  VM0_BARRIER();
  int buf = 0;
  for (int t = 0; t < NT; ++t) {
    if (t + 1 < NT) STAGE(buf ^ 1, (t + 1) * BK);  // issue-early
    COMPUTE(buf);
    if (t + 1 < NT) VM0_BARRIER();
    buf ^= 1;
  }

  // epilogue: H = silu(g)*u  (C/D: col=lane&15, row=(lane>>4)*4+r)
#pragma unroll
  for (int i = 0; i < 8; ++i) {
#pragma unroll
    for (int r = 0; r < 4; ++r) {
      int mrow = wm * 128 + i * 16 + (lane >> 4) * 4 + r;
      if (mrow < rv) {
        _Float16* hp = H + (size_t)(hbase + mrow) * D_FF + n0 + wn * 32 + la;
#pragma unroll
        for (int j = 0; j < 2; ++j) {
          float g = accg[i][j][r], u = accu[i][j][r];
          hp[j * 16] = (_Float16)(g / (1.f + expf(-g)) * u);
        }
      }
    }
  }
}

// Down-proj: tile 128 rows x 256 cols, 8 waves (2Mx4N), per-wave 64x64.
// LDS buffer 48KB: A[128][64]@0, B[256][64]@16K. Scatter atomicAdd epilogue.
__global__ __launch_bounds__(512) void down_mfma(
    const _Float16* __restrict__ Hb, const _Float16* __restrict__ wdh,
    const int* __restrict__ counts, const int* __restrict__ offsets,
    const int* __restrict__ list_tok, const float* __restrict__ list_w,
    float* __restrict__ out, int T) {
  extern __shared__ char lds[];
  const uint32_t LB = (uint32_t)(uintptr_t)lds;
  int e = blockIdx.x >> 5, tile = blockIdx.x & 31;
  int cnt = counts[e];
  int row0 = tile * 128;
  if (row0 >= cnt) return;
  int rv = cnt - row0; if (rv > 128) rv = 128;
  int hbase = offsets[e] + row0;
  int n0 = blockIdx.y * 256;

  int tid = threadIdx.x, wave = tid >> 6, lane = tid & 63;
  int wm = wave >> 2, wn = wave & 3, la = lane & 15;

  int swz = ((lane & 7) ^ ((lane >> 3) & 7)) << 4;
  const char *sA[2], *sB[4];
  const _Float16* wd_e = wdh + (size_t)e * D_MODEL * D_FF;
#pragma unroll
  for (int c = 0; c < 2; ++c) {
    int row = c * 64 + wave * 8 + (lane >> 3);
    int ra = row < rv ? row : (rv - 1);
    sA[c] = (const char*)(Hb + (size_t)(hbase + ra) * D_FF) + swz;
  }
#pragma unroll
  for (int c = 0; c < 4; ++c) {
    int row = n0 + c * 64 + wave * 8 + (lane >> 3);
    sB[c] = (const char*)(wd_e + (size_t)row * D_FF) + swz;
  }
  uint32_t dA = wave * 1024;

  uint32_t xr_ = (uint32_t)((la & 7) << 4);
  uint32_t colB[2];
#pragma unroll
  for (int kk = 0; kk < 2; ++kk)
    colB[kk] = (uint32_t)(((kk * 64 + (lane >> 4) * 16)) ^ xr_);
  uint32_t aRow[4], bRow[4];
#pragma unroll
  for (int i = 0; i < 4; ++i) aRow[i] = (uint32_t)((wm * 64 + i * 16 + la) * 128);
#pragma unroll
  for (int j = 0; j < 4; ++j) bRow[j] = 16384u + (uint32_t)((wn * 64 + j * 16 + la) * 128);

  f32x4 acc[4][4] = {};

  auto STAGE = [&](int buf, int k0) {
    uint32_t db = LB + (uint32_t)buf * 49152u;
#pragma unroll
    for (int c = 0; c < 2; ++c) gload16(sA[c] + k0 * 2, db + c * 8192 + dA);
#pragma unroll
    for (int c = 0; c < 4; ++c) gload16(sB[c] + k0 * 2, db + 16384 + c * 8192 + dA);
  };
  auto COMPUTE = [&](int buf) {
    uint32_t bb = LB + (uint32_t)buf * 49152u;
#pragma unroll
    for (int kk = 0; kk < 2; ++kk) {
      uint32_t cb = colB[kk];
      f16x8 b[4], a[4];
#pragma unroll
      for (int j = 0; j < 4; ++j) b[j] = ldsr(bb + bRow[j] + cb);
#pragma unroll
      for (int i = 0; i < 4; ++i) a[i] = ldsr(bb + aRow[i] + cb);
      LGKM0_FENCE();
      __builtin_amdgcn_s_setprio(1);
#pragma unroll
      for (int i = 0; i < 4; ++i)
#pragma unroll
        for (int j = 0; j < 4; ++j)
          acc[i][j] = __builtin_amdgcn_mfma_f32_16x16x32_f16(a[i], b[j], acc[i][j], 0, 0, 0);
      __builtin_amdgcn_s_setprio(0);
    }
  };

  const int NT = D_FF / BK;  // 32
  STAGE(0, 0);
  VM0_BARRIER();
  int buf = 0;
  for (int t = 0; t < NT; ++t) {
    if (t + 1 < NT) STAGE(buf ^ 1, (t + 1) * BK);
    COMPUTE(buf);
    if (t + 1 < NT) VM0_BARRIER();
    buf ^= 1;
  }

#pragma unroll
  for (int i = 0; i < 4; ++i) {
#pragma unroll
    for (int r = 0; r < 4; ++r) {
      int mrow = wm * 64 + i * 16 + (lane >> 4) * 4 + r;
      if (mrow < rv) {
        int li = e * T + row0 + mrow;
        float w = list_w[li];
        int tok = list_tok[li];
        float* op = out + (size_t)tok * D_MODEL + n0 + wn * 64 + la;
#pragma unroll
        for (int j = 0; j < 4; ++j) atomicAdd(op + j * 16, w * acc[i][j][r]);
      }
    }
  }
}

extern "C" void kernel_launch(void* const* d_in, const int* in_sizes, int n_in,
                              void* d_out, int out_size, void* d_ws, size_t ws_size,
                              hipStream_t stream) {
  const float* x        = (const float*)d_in[0];
  const float* w_router = (const float*)d_in[1];
  const float* w_gate   = (const float*)d_in[2];
  const float* w_up     = (const float*)d_in[3];
  const float* w_down   = (const float*)d_in[4];
  float* out = (float*)d_out;
  int T = in_sizes[0] / D_MODEL;  // 4096

  const size_t MB = 1048576;
  char* ws = (char*)d_ws;
  float* P_acc    = (float*)ws;
  int*   counts   = (int*)(ws + 32);
  int*   offsets  = (int*)(ws + 64);
  int*   list_tok = (int*)(ws + 4096);
  float* list_w   = (float*)(ws + 4096 + 131072);
  _Float16* xh  = (_Float16*)(ws + 1 * MB);
  _Float16* wgh = (_Float16*)(ws + 9 * MB);
  _Float16* wuh = (_Float16*)(ws + 41 * MB);
  _Float16* wdh = (_Float16*)(ws + 73 * MB);
  _Float16* H   = (_Float16*)(ws + 105 * MB);

  hipFuncSetAttribute(reinterpret_cast<const void*>(glu_fused),
                      hipFuncAttributeMaxDynamicSharedMemorySize, 131072);
  hipFuncSetAttribute(reinterpret_cast<const void*>(down_mfma),
                      hipFuncAttributeMaxDynamicSharedMemorySize, 98304);

  int n_out = T * D_MODEL + 1;
  init_kernel<<<(n_out + 255) / 256, 256, 0, stream>>>(out, n_out, (int*)ws);
  conv_w<<<2048, 256, 0, stream>>>(
      (const float4*)w_gate, (const float4*)w_up, (const float4*)w_down,
      (f16x4*)wgh, (f16x4*)wuh, (f16x4*)wdh, NE * D_FF * D_MODEL / 4);
  router_kernel<<<T, 64, 0, stream>>>(x, w_router, P_acc, counts, list_tok, list_w, xh, T);
  finalize_router<<<1, 64, 0, stream>>>(P_acc, counts, offsets, out + (size_t)T * D_MODEL, T);
  // glu: x = e*16 + rowtile (256 rows each, covers 4096 rows/expert), y = col panel
  glu_fused<<<dim3(NE * 16, D_FF / 128), 512, 131072, stream>>>(
      xh, wgh, wuh, counts, offsets, list_tok, H, T);
  // down: x = e*32 + rowtile (128 rows each), y = col panel (256)
  down_mfma<<<dim3(NE * 32, D_MODEL / 256), 512, 98304, stream>>>(
      H, wdh, counts, offsets, list_tok, list_w, out, T);
}

// Round 8
// 595.991 us; speedup vs baseline: 3.5744x; 1.3702x over previous
//
#include <hip/hip_runtime.h>
#include <hip/hip_bf16.h>
#include <math.h>
#include <stdint.h>

// MoE top-2 GLU, MI355X round 8: occupancy-first m97-style GEMMs.
// - worklist of active 128-row tiles (built in finalize_router) -> no dead blocks
// - glu: 128x(64g+64u), 32KB single-buffered LDS, 256thr/4 waves, plain syncthreads
// - down: 128x64, 24KB LDS. 3-5 resident blocks/CU hide barrier drains via TLP.
//
// ws layout (bytes):
//   [0,32) float P_acc[8]; [32,64) int counts[8]; [64,96) int offsets[8]
//   [96,100) int n_tiles;  [1024,+384) int wl[96] (packed e<<20|row0)
//   [4K,+128K) int list_tok[8*T]; [4K+128K,+128K) float list_w[8*T]
//   [1M,9M)    fp16 xh[T][1024]
//   [9M,41M)   fp16 wgh[8][2048][1024]
//   [41M,73M)  fp16 wuh[8][2048][1024]
//   [73M,105M) fp16 wdh[8][1024][2048]
//   [105M,137M) fp16 H[8192][2048]

#define D_MODEL 1024
#define D_FF    2048
#define NE      8
#define BK      64
#define NTILES_MAX 72

typedef _Float16 f16x8 __attribute__((ext_vector_type(8)));
typedef _Float16 f16x4 __attribute__((ext_vector_type(4)));
typedef float    f32x4 __attribute__((ext_vector_type(4)));

__device__ __forceinline__ void gload16(const void* src, uint32_t ldsoff) {
  __builtin_amdgcn_global_load_lds(
      (const __attribute__((address_space(1))) uint32_t*)(uintptr_t)src,
      (__attribute__((address_space(3))) uint32_t*)(uintptr_t)ldsoff,
      16, 0, 0);
}

__global__ __launch_bounds__(256) void init_kernel(float* __restrict__ out, int n,
                                                   int* __restrict__ ws0) {
  int i = blockIdx.x * 256 + threadIdx.x;
  if (i < n) out[i] = 0.f;
  if (blockIdx.x == 0 && threadIdx.x < 32) ws0[threadIdx.x] = 0;  // P_acc + counts
}

__global__ __launch_bounds__(256) void conv_w(
    const float4* __restrict__ a, const float4* __restrict__ b,
    const float4* __restrict__ c, f16x4* __restrict__ da,
    f16x4* __restrict__ db, f16x4* __restrict__ dc, int n4) {
  int stride = gridDim.x * 256;
  for (int i = blockIdx.x * 256 + threadIdx.x; i < n4; i += stride) {
    float4 v = a[i];
    f16x4 h; h[0] = (_Float16)v.x; h[1] = (_Float16)v.y; h[2] = (_Float16)v.z; h[3] = (_Float16)v.w;
    da[i] = h;
    v = b[i];
    h[0] = (_Float16)v.x; h[1] = (_Float16)v.y; h[2] = (_Float16)v.z; h[3] = (_Float16)v.w;
    db[i] = h;
    v = c[i];
    h[0] = (_Float16)v.x; h[1] = (_Float16)v.y; h[2] = (_Float16)v.z; h[3] = (_Float16)v.w;
    dc[i] = h;
  }
}

__global__ __launch_bounds__(64) void router_kernel(
    const float* __restrict__ x, const float* __restrict__ wr,
    float* __restrict__ P_acc, int* __restrict__ counts,
    int* __restrict__ list_tok, float* __restrict__ list_w,
    _Float16* __restrict__ xh, int T) {
  int t = blockIdx.x;
  int lane = threadIdx.x;
  const float4* xr = reinterpret_cast<const float4*>(x + (size_t)t * D_MODEL);
  f16x4* xo = reinterpret_cast<f16x4*>(xh + (size_t)t * D_MODEL);
  float4 xv[4];
#pragma unroll
  for (int j = 0; j < 4; ++j) {
    xv[j] = xr[lane + 64 * j];
    f16x4 h; h[0] = (_Float16)xv[j].x; h[1] = (_Float16)xv[j].y;
    h[2] = (_Float16)xv[j].z; h[3] = (_Float16)xv[j].w;
    xo[lane + 64 * j] = h;
  }

  float logit[NE];
#pragma unroll
  for (int e = 0; e < NE; ++e) {
    const float4* wrow = reinterpret_cast<const float4*>(wr + e * D_MODEL);
    float s = 0.f;
#pragma unroll
    for (int j = 0; j < 4; ++j) {
      float4 w4 = wrow[lane + 64 * j];
      s += xv[j].x * w4.x + xv[j].y * w4.y + xv[j].z * w4.z + xv[j].w * w4.w;
    }
#pragma unroll
    for (int off = 32; off > 0; off >>= 1) s += __shfl_xor(s, off, 64);
    logit[e] = s;
  }

  float m = logit[0];
#pragma unroll
  for (int e = 1; e < NE; ++e) m = fmaxf(m, logit[e]);
  float p[NE], sum = 0.f;
#pragma unroll
  for (int e = 0; e < NE; ++e) { p[e] = expf(logit[e] - m); sum += p[e]; }
  float inv = 1.f / sum;
#pragma unroll
  for (int e = 0; e < NE; ++e) p[e] *= inv;

  float v0 = -1.f; int i0 = 0;
#pragma unroll
  for (int e = 0; e < NE; ++e) if (p[e] > v0) { v0 = p[e]; i0 = e; }
  float v1 = -1.f; int i1 = 0;
#pragma unroll
  for (int e = 0; e < NE; ++e) if (e != i0 && p[e] > v1) { v1 = p[e]; i1 = e; }
  float rs = 1.f / (v0 + v1);

  if (lane < NE) atomicAdd(&P_acc[lane], p[lane]);
  if (lane == 0) {
    int pos0 = atomicAdd(&counts[i0], 1);
    list_tok[i0 * T + pos0] = t;
    list_w[i0 * T + pos0] = v0 * rs;
    int pos1 = atomicAdd(&counts[i1], 1);
    list_tok[i1 * T + pos1] = t;
    list_w[i1 * T + pos1] = v1 * rs;
  }
}

// offsets, aux, and the active-tile worklist (128-row tiles, packed e<<20|row0).
__global__ void finalize_router(const float* __restrict__ P_acc,
                                const int* __restrict__ counts,
                                int* __restrict__ offsets,
                                int* __restrict__ n_tiles, int* __restrict__ wl,
                                float* __restrict__ out_aux, int T) {
  if (threadIdx.x == 0 && blockIdx.x == 0) {
    int off = 0; float aux = 0.f; float invT = 1.f / (float)T; int nt = 0;
    for (int e = 0; e < NE; ++e) {
      offsets[e] = off;
      for (int r = 0; r < counts[e]; r += 128) wl[nt++] = (e << 20) | r;
      off += counts[e];
      aux += ((float)counts[e] * invT) * (P_acc[e] * invT);
    }
    n_tiles[0] = nt;
    out_aux[0] = aux * (float)NE * 0.01f;
  }
}

// Fused gate+up: 128 rows x (64 gate + 64 up) cols, K=1024.
// LDS 32KB single-buffered: A[128][64]@0 (16K), G[64][64]@16K (8K), U@24K (8K).
// 256 threads = 4 waves (2Mx2N): wave tile 64 rows x 32 cols (of each g,u).
__global__ __launch_bounds__(256) void glu_fused(
    const _Float16* __restrict__ xh, const _Float16* __restrict__ wgh,
    const _Float16* __restrict__ wuh, const int* __restrict__ n_tiles,
    const int* __restrict__ wl, const int* __restrict__ counts,
    const int* __restrict__ offsets, const int* __restrict__ list_tok,
    _Float16* __restrict__ H, int T) {
  __shared__ char lds[32768];
  int bx = blockIdx.x;
  if (bx >= n_tiles[0]) return;
  int packed = wl[bx];
  int e = packed >> 20, row0 = packed & 0xFFFFF;
  int cnt = counts[e];
  int rv = cnt - row0; if (rv > 128) rv = 128;
  int hbase = offsets[e] + row0;
  int n0 = blockIdx.y * 64;

  const uint32_t LB = (uint32_t)(uintptr_t)lds;
  int tid = threadIdx.x, wave = tid >> 6, lane = tid & 63;
  int wm = wave >> 1, wn = wave & 1, la = lane & 15;

  // stage: LDS[row][slot]=global[row][slot^(row&7)] via inverse-swizzled source
  int swz = ((lane & 7) ^ (lane >> 3)) << 4;
  const char *sA[4], *sG[2], *sU[2];
  const _Float16* wg_e = wgh + (size_t)e * D_FF * D_MODEL;
  const _Float16* wu_e = wuh + (size_t)e * D_FF * D_MODEL;
#pragma unroll
  for (int c = 0; c < 4; ++c) {
    int row = c * 32 + (tid >> 3);
    int ra = row < rv ? row : (rv - 1);
    int tok = list_tok[e * T + row0 + ra];
    sA[c] = (const char*)(xh + (size_t)tok * D_MODEL) + swz;
  }
#pragma unroll
  for (int c = 0; c < 2; ++c) {
    int row = n0 + c * 32 + (tid >> 3);
    sG[c] = (const char*)(wg_e + (size_t)row * D_MODEL) + swz;
    sU[c] = (const char*)(wu_e + (size_t)row * D_MODEL) + swz;
  }
  uint32_t dA = wave * 1024;

  // swizzled read offsets (row&7 == la&7 for all fragment rows)
  int colB[2];
#pragma unroll
  for (int kk = 0; kk < 2; ++kk)
    colB[kk] = (kk * 64 + (lane >> 4) * 16) ^ ((la & 7) << 4);
  int aRow[4], gOff[2], uOff[2];
#pragma unroll
  for (int i = 0; i < 4; ++i) aRow[i] = (wm * 64 + i * 16 + la) * 128;
#pragma unroll
  for (int j = 0; j < 2; ++j) {
    gOff[j] = 16384 + (wn * 32 + j * 16 + la) * 128;
    uOff[j] = 24576 + (wn * 32 + j * 16 + la) * 128;
  }

  f32x4 accg[4][2] = {}, accu[4][2] = {};

  for (int k0 = 0; k0 < D_MODEL; k0 += BK) {
#pragma unroll
    for (int c = 0; c < 4; ++c) gload16(sA[c] + k0 * 2, LB + c * 4096 + dA);
#pragma unroll
    for (int c = 0; c < 2; ++c) {
      gload16(sG[c] + k0 * 2, LB + 16384 + c * 4096 + dA);
      gload16(sU[c] + k0 * 2, LB + 24576 + c * 4096 + dA);
    }
    __syncthreads();
#pragma unroll
    for (int kk = 0; kk < 2; ++kk) {
      f16x8 a[4], bg[2], bu[2];
#pragma unroll
      for (int i = 0; i < 4; ++i) a[i] = *(const f16x8*)(lds + aRow[i] + colB[kk]);
#pragma unroll
      for (int j = 0; j < 2; ++j) {
        bg[j] = *(const f16x8*)(lds + gOff[j] + colB[kk]);
        bu[j] = *(const f16x8*)(lds + uOff[j] + colB[kk]);
      }
#pragma unroll
      for (int i = 0; i < 4; ++i)
#pragma unroll
        for (int j = 0; j < 2; ++j) {
          accg[i][j] = __builtin_amdgcn_mfma_f32_16x16x32_f16(a[i], bg[j], accg[i][j], 0, 0, 0);
          accu[i][j] = __builtin_amdgcn_mfma_f32_16x16x32_f16(a[i], bu[j], accu[i][j], 0, 0, 0);
        }
    }
    __syncthreads();
  }

  // epilogue: H = silu(g)*u  (C/D: col=lane&15, row=(lane>>4)*4+r)
#pragma unroll
  for (int i = 0; i < 4; ++i) {
#pragma unroll
    for (int r = 0; r < 4; ++r) {
      int mrow = wm * 64 + i * 16 + (lane >> 4) * 4 + r;
      if (mrow < rv) {
        _Float16* hp = H + (size_t)(hbase + mrow) * D_FF + n0 + wn * 32 + la;
#pragma unroll
        for (int j = 0; j < 2; ++j) {
          float g = accg[i][j][r], u = accu[i][j][r];
          hp[j * 16] = (_Float16)(g / (1.f + expf(-g)) * u);
        }
      }
    }
  }
}

// Down-proj: 128 rows x 64 out-cols, K=2048. LDS 24KB: A[128][64]@0, B[64][64]@16K.
// 256 threads = 4 waves (2x2), wave tile 64x32. Scatter atomicAdd epilogue.
__global__ __launch_bounds__(256) void down_mfma(
    const _Float16* __restrict__ Hb, const _Float16* __restrict__ wdh,
    const int* __restrict__ n_tiles, const int* __restrict__ wl,
    const int* __restrict__ counts, const int* __restrict__ offsets,
    const int* __restrict__ list_tok, const float* __restrict__ list_w,
    float* __restrict__ out, int T) {
  __shared__ char lds[24576];
  int bx = blockIdx.x;
  if (bx >= n_tiles[0]) return;
  int packed = wl[bx];
  int e = packed >> 20, row0 = packed & 0xFFFFF;
  int cnt = counts[e];
  int rv = cnt - row0; if (rv > 128) rv = 128;
  int hbase = offsets[e] + row0;
  int n0 = blockIdx.y * 64;

  const uint32_t LB = (uint32_t)(uintptr_t)lds;
  int tid = threadIdx.x, wave = tid >> 6, lane = tid & 63;
  int wm = wave >> 1, wn = wave & 1, la = lane & 15;

  int swz = ((lane & 7) ^ (lane >> 3)) << 4;
  const char *sA[4], *sB[2];
  const _Float16* wd_e = wdh + (size_t)e * D_MODEL * D_FF;
#pragma unroll
  for (int c = 0; c < 4; ++c) {
    int row = c * 32 + (tid >> 3);
    int ra = row < rv ? row : (rv - 1);
    sA[c] = (const char*)(Hb + (size_t)(hbase + ra) * D_FF) + swz;
  }
#pragma unroll
  for (int c = 0; c < 2; ++c) {
    int row = n0 + c * 32 + (tid >> 3);
    sB[c] = (const char*)(wd_e + (size_t)row * D_FF) + swz;
  }
  uint32_t dA = wave * 1024;

  int colB[2];
#pragma unroll
  for (int kk = 0; kk < 2; ++kk)
    colB[kk] = (kk * 64 + (lane >> 4) * 16) ^ ((la & 7) << 4);
  int aRow[4], bOff[2];
#pragma unroll
  for (int i = 0; i < 4; ++i) aRow[i] = (wm * 64 + i * 16 + la) * 128;
#pragma unroll
  for (int j = 0; j < 2; ++j) bOff[j] = 16384 + (wn * 32 + j * 16 + la) * 128;

  f32x4 acc[4][2] = {};

  for (int k0 = 0; k0 < D_FF; k0 += BK) {
#pragma unroll
    for (int c = 0; c < 4; ++c) gload16(sA[c] + k0 * 2, LB + c * 4096 + dA);
#pragma unroll
    for (int c = 0; c < 2; ++c) gload16(sB[c] + k0 * 2, LB + 16384 + c * 4096 + dA);
    __syncthreads();
#pragma unroll
    for (int kk = 0; kk < 2; ++kk) {
      f16x8 a[4], b[2];
#pragma unroll
      for (int i = 0; i < 4; ++i) a[i] = *(const f16x8*)(lds + aRow[i] + colB[kk]);
#pragma unroll
      for (int j = 0; j < 2; ++j) b[j] = *(const f16x8*)(lds + bOff[j] + colB[kk]);
#pragma unroll
      for (int i = 0; i < 4; ++i)
#pragma unroll
        for (int j = 0; j < 2; ++j)
          acc[i][j] = __builtin_amdgcn_mfma_f32_16x16x32_f16(a[i], b[j], acc[i][j], 0, 0, 0);
    }
    __syncthreads();
  }

#pragma unroll
  for (int i = 0; i < 4; ++i) {
#pragma unroll
    for (int r = 0; r < 4; ++r) {
      int mrow = wm * 64 + i * 16 + (lane >> 4) * 4 + r;
      if (mrow < rv) {
        int li = e * T + row0 + mrow;
        float w = list_w[li];
        int tok = list_tok[li];
        float* op = out + (size_t)tok * D_MODEL + n0 + wn * 32 + la;
#pragma unroll
        for (int j = 0; j < 2; ++j) atomicAdd(op + j * 16, w * acc[i][j][r]);
      }
    }
  }
}

extern "C" void kernel_launch(void* const* d_in, const int* in_sizes, int n_in,
                              void* d_out, int out_size, void* d_ws, size_t ws_size,
                              hipStream_t stream) {
  const float* x        = (const float*)d_in[0];
  const float* w_router = (const float*)d_in[1];
  const float* w_gate   = (const float*)d_in[2];
  const float* w_up     = (const float*)d_in[3];
  const float* w_down   = (const float*)d_in[4];
  float* out = (float*)d_out;
  int T = in_sizes[0] / D_MODEL;  // 4096

  const size_t MB = 1048576;
  char* ws = (char*)d_ws;
  float* P_acc    = (float*)ws;
  int*   counts   = (int*)(ws + 32);
  int*   offsets  = (int*)(ws + 64);
  int*   n_tiles  = (int*)(ws + 96);
  int*   wl       = (int*)(ws + 1024);
  int*   list_tok = (int*)(ws + 4096);
  float* list_w   = (float*)(ws + 4096 + 131072);
  _Float16* xh  = (_Float16*)(ws + 1 * MB);
  _Float16* wgh = (_Float16*)(ws + 9 * MB);
  _Float16* wuh = (_Float16*)(ws + 41 * MB);
  _Float16* wdh = (_Float16*)(ws + 73 * MB);
  _Float16* H   = (_Float16*)(ws + 105 * MB);

  int n_out = T * D_MODEL + 1;
  init_kernel<<<(n_out + 255) / 256, 256, 0, stream>>>(out, n_out, (int*)ws);
  conv_w<<<2048, 256, 0, stream>>>(
      (const float4*)w_gate, (const float4*)w_up, (const float4*)w_down,
      (f16x4*)wgh, (f16x4*)wuh, (f16x4*)wdh, NE * D_FF * D_MODEL / 4);
  router_kernel<<<T, 64, 0, stream>>>(x, w_router, P_acc, counts, list_tok, list_w, xh, T);
  finalize_router<<<1, 64, 0, stream>>>(P_acc, counts, offsets, n_tiles, wl,
                                        out + (size_t)T * D_MODEL, T);
  glu_fused<<<dim3(NTILES_MAX, D_FF / 64), 256, 0, stream>>>(
      xh, wgh, wuh, n_tiles, wl, counts, offsets, list_tok, H, T);
  down_mfma<<<dim3(NTILES_MAX, D_MODEL / 64), 256, 0, stream>>>(
      H, wdh, n_tiles, wl, counts, offsets, list_tok, list_w, out, T);
}